// Round 1
// baseline (5100.929 us; speedup 1.0000x reference)
//
#include <hip/hip_runtime.h>
#include <cstdint>
#include <cstddef>

// ---------------------------------------------------------------------------
// SparseCINConv: 3 levels of {segment_sum aggregation -> 2x MLP(64->64->64 with
// BatchNorm(batch stats)+ReLU) -> concat -> Linear(128->64)+BN+ReLU}
// All fp32. BN stats fused into GEMM epilogues; consumers derive coeffs.
// ---------------------------------------------------------------------------

__global__ __launch_bounds__(256) void scatter_add_k(
    const float* __restrict__ xsrc, const int* __restrict__ srcIdx,
    const int* __restrict__ dstIdx, float* __restrict__ agg, int E)
{
    int tid = blockIdx.x * 256 + threadIdx.x;
    if (tid >= E * 16) return;
    int e  = tid >> 4;
    int f4 = tid & 15;
    int s = srcIdx[e];
    int d = dstIdx[e];
    const float4 v = *(const float4*)(xsrc + (size_t)s * 64 + f4 * 4);
    float* dp = agg + (size_t)d * 64 + f4 * 4;
    unsafeAtomicAdd(dp + 0, v.x);
    unsafeAtomicAdd(dp + 1, v.y);
    unsafeAtomicAdd(dp + 2, v.z);
    unsafeAtomicAdd(dp + 3, v.w);
}

// mode 0: in = (in0 ? in0 : 0) + (1+eps[epsIdx]) * in1          (K=64)
// mode 1: in = relu(bn(in0)) via st0/g0/be0                      (K=64)
// mode 2: in = concat(relu(bn(in0)), relu(bn(in1)))              (K=128)
// out = in @ W + bias ; ostats[0:64]+=colsum(out), ostats[64:128]+=colsumsq(out)
__global__ __launch_bounds__(256) void gemm_bn_k(
    int mode,
    const float* in0, const float* in1,
    const float* __restrict__ st0, const float* __restrict__ g0, const float* __restrict__ be0,
    const float* __restrict__ st1, const float* __restrict__ g1, const float* __restrict__ be1,
    const float* __restrict__ epsP, int epsIdx,
    const float* __restrict__ W, const float* __restrict__ bias,
    float* out, float* __restrict__ ostats, int N)
{
    __shared__ float sIn[64][68];   // padded to avoid bank conflicts
    __shared__ float sW[64][64];
    __shared__ float sCoef[4][64];  // a0,c0,a1,c1
    __shared__ float sBias[64];
    __shared__ float sRed[16][64];

    const int tid = threadIdx.x;
    const int tx = tid & 15, ty = tid >> 4;
    const int row0 = blockIdx.x * 64;
    const float Nf = (float)N;

    if (tid < 64) {
        sBias[tid] = bias[tid];
        if (mode >= 1) {
            float s = st0[tid], sq = st0[64 + tid];
            float m = s / Nf;
            float v = sq / Nf - m * m;
            float a = g0[tid] * rsqrtf(v + 1e-5f);
            sCoef[0][tid] = a;
            sCoef[1][tid] = be0[tid] - a * m;
        }
    } else if (tid < 128 && mode == 2) {
        int k = tid - 64;
        float s = st1[k], sq = st1[64 + k];
        float m = s / Nf;
        float v = sq / Nf - m * m;
        float a = g1[k] * rsqrtf(v + 1e-5f);
        sCoef[2][k] = a;
        sCoef[3][k] = be1[k] - a * m;
    }
    float sx = 0.f;
    if (mode == 0) sx = 1.0f + epsP[epsIdx];
    __syncthreads();

    float acc[4][4] = {};
    const int nch = (mode == 2) ? 2 : 1;
    for (int ch = 0; ch < nch; ++ch) {
        // ---- stage processed input tile (64 rows x 64 k-cols) ----
        for (int t = tid; t < 1024; t += 256) {
            int r = t >> 4, f4 = t & 15;
            int gr = row0 + r;
            int col = f4 * 4;
            float4 v = make_float4(0.f, 0.f, 0.f, 0.f);
            if (gr < N) {
                if (mode == 0) {
                    float4 xv = *(const float4*)(in1 + (size_t)gr * 64 + col);
                    v.x = sx * xv.x; v.y = sx * xv.y; v.z = sx * xv.z; v.w = sx * xv.w;
                    if (in0) {
                        float4 av = *(const float4*)(in0 + (size_t)gr * 64 + col);
                        v.x += av.x; v.y += av.y; v.z += av.z; v.w += av.w;
                    }
                } else {
                    const float* base = (ch == 0) ? in0 : in1;
                    float4 yv = *(const float4*)(base + (size_t)gr * 64 + col);
                    int ci = ch * 2;
                    v.x = fmaxf(sCoef[ci][col+0]*yv.x + sCoef[ci+1][col+0], 0.f);
                    v.y = fmaxf(sCoef[ci][col+1]*yv.y + sCoef[ci+1][col+1], 0.f);
                    v.z = fmaxf(sCoef[ci][col+2]*yv.z + sCoef[ci+1][col+2], 0.f);
                    v.w = fmaxf(sCoef[ci][col+3]*yv.w + sCoef[ci+1][col+3], 0.f);
                }
            }
            *(float4*)&sIn[r][col] = v;
        }
        // ---- stage W chunk (64 x 64) ----
        for (int t = tid; t < 1024; t += 256) {
            int r = t >> 4, f4 = t & 15;
            *(float4*)&sW[r][f4 * 4] =
                *(const float4*)(W + (size_t)(ch * 64 + r) * 64 + f4 * 4);
        }
        __syncthreads();
        // ---- compute: 4x4 register tile ----
        #pragma unroll
        for (int kb = 0; kb < 64; kb += 4) {
            float4 xf[4], wf[4];
            #pragma unroll
            for (int i = 0; i < 4; ++i) xf[i] = *(const float4*)&sIn[4*ty + i][kb];
            #pragma unroll
            for (int kk = 0; kk < 4; ++kk) wf[kk] = *(const float4*)&sW[kb + kk][4*tx];
            const float* xff = (const float*)xf;
            const float* wff = (const float*)wf;
            #pragma unroll
            for (int kk = 0; kk < 4; ++kk) {
                #pragma unroll
                for (int i = 0; i < 4; ++i) {
                    float xv = xff[i*4 + kk];
                    #pragma unroll
                    for (int j = 0; j < 4; ++j)
                        acc[i][j] = fmaf(xv, wff[kk*4 + j], acc[i][j]);
                }
            }
        }
        __syncthreads();
    }

    // ---- epilogue: bias add, store, column stats ----
    float ps[4] = {0,0,0,0}, pq[4] = {0,0,0,0};
    #pragma unroll
    for (int i = 0; i < 4; ++i) {
        int gr = row0 + 4*ty + i;
        if (gr < N) {
            float4 o;
            o.x = acc[i][0] + sBias[4*tx+0];
            o.y = acc[i][1] + sBias[4*tx+1];
            o.z = acc[i][2] + sBias[4*tx+2];
            o.w = acc[i][3] + sBias[4*tx+3];
            *(float4*)(out + (size_t)gr * 64 + 4*tx) = o;
            ps[0]+=o.x; ps[1]+=o.y; ps[2]+=o.z; ps[3]+=o.w;
            pq[0]+=o.x*o.x; pq[1]+=o.y*o.y; pq[2]+=o.z*o.z; pq[3]+=o.w*o.w;
        }
    }
    *(float4*)&sRed[ty][4*tx] = make_float4(ps[0],ps[1],ps[2],ps[3]);
    __syncthreads();
    if (tid < 64) {
        float s = 0.f;
        #pragma unroll
        for (int t = 0; t < 16; ++t) s += sRed[t][tid];
        unsafeAtomicAdd(&ostats[tid], s);
    }
    __syncthreads();
    *(float4*)&sRed[ty][4*tx] = make_float4(pq[0],pq[1],pq[2],pq[3]);
    __syncthreads();
    if (tid < 64) {
        float s = 0.f;
        #pragma unroll
        for (int t = 0; t < 16; ++t) s += sRed[t][tid];
        unsafeAtomicAdd(&ostats[64 + tid], s);
    }
}

__global__ __launch_bounds__(256) void bn_relu_apply_k(
    const float* __restrict__ y, const float* __restrict__ st,
    const float* __restrict__ g, const float* __restrict__ be,
    float* __restrict__ out, int N)
{
    __shared__ float sa[64], sc[64];
    int tid = threadIdx.x;
    if (tid < 64) {
        float s = st[tid], sq = st[64 + tid];
        float m = s / (float)N;
        float v = sq / (float)N - m * m;
        float a = g[tid] * rsqrtf(v + 1e-5f);
        sa[tid] = a;
        sc[tid] = be[tid] - a * m;
    }
    __syncthreads();
    int idx = blockIdx.x * 256 + tid;
    if (idx < N * 16) {
        int r = idx >> 4, f4 = idx & 15, col = f4 * 4;
        float4 v = *(const float4*)(y + (size_t)r * 64 + col);
        float4 o;
        o.x = fmaxf(sa[col+0]*v.x + sc[col+0], 0.f);
        o.y = fmaxf(sa[col+1]*v.y + sc[col+1], 0.f);
        o.z = fmaxf(sa[col+2]*v.z + sc[col+2], 0.f);
        o.w = fmaxf(sa[col+3]*v.w + sc[col+3], 0.f);
        *(float4*)(out + (size_t)r * 64 + col) = o;
    }
}

extern "C" void kernel_launch(void* const* d_in, const int* in_sizes, int n_in,
                              void* d_out, int out_size, void* d_ws, size_t ws_size,
                              hipStream_t stream) {
    (void)n_in; (void)out_size; (void)ws_size;
    const float* x0 = (const float*)d_in[0];
    const float* x1 = (const float*)d_in[1];
    const float* x2 = (const float*)d_in[2];
    const int* up_index0 = (const int*)d_in[3];
    const int* up_index1 = (const int*)d_in[4];
    const int* bnd_src1  = (const int*)d_in[5];
    const int* bnd_dst1  = (const int*)d_in[6];
    const int* bnd_src2  = (const int*)d_in[7];
    const int* bnd_dst2  = (const int*)d_in[8];
    const float* up_W1 = (const float*)d_in[9];
    const float* up_b1 = (const float*)d_in[10];
    const float* up_g1 = (const float*)d_in[11];
    const float* up_be1= (const float*)d_in[12];
    const float* up_W2 = (const float*)d_in[13];
    const float* up_b2 = (const float*)d_in[14];
    const float* up_g2 = (const float*)d_in[15];
    const float* up_be2= (const float*)d_in[16];
    const float* bd_W1 = (const float*)d_in[17];
    const float* bd_b1 = (const float*)d_in[18];
    const float* bd_g1 = (const float*)d_in[19];
    const float* bd_be1= (const float*)d_in[20];
    const float* bd_W2 = (const float*)d_in[21];
    const float* bd_b2 = (const float*)d_in[22];
    const float* bd_g2 = (const float*)d_in[23];
    const float* bd_be2= (const float*)d_in[24];
    const float* cmb_W = (const float*)d_in[25];
    const float* cmb_b = (const float*)d_in[26];
    const float* cmb_g = (const float*)d_in[27];
    const float* cmb_be= (const float*)d_in[28];
    const float* epsP  = (const float*)d_in[29];

    const int EU0 = in_sizes[3] / 2, EU1 = in_sizes[4] / 2;
    const int EB1 = in_sizes[5],     EB2 = in_sizes[7];
    const int n0 = in_sizes[0] / 64, n1 = in_sizes[1] / 64, n2 = in_sizes[2] / 64;

    float* bufA  = (float*)d_ws;                      // max-N sized up-branch buffer
    float* stats = bufA + (size_t)n1 * 64;            // 15 * 128 floats
    float* outP  = (float*)d_out;

    hipMemsetAsync(stats, 0, 15 * 128 * sizeof(float), stream);

    auto S = [&](int d, int i) { return stats + (size_t)(d * 5 + i) * 128; };

    auto runLevel = [&](int d, const float* x, int N,
                        const int* upSrc, const int* upDst, int upE,
                        const float* bdX, const int* bdSrc, const int* bdDst, int bdE,
                        float* bufB /* == this level's out region */) {
        dim3 gblk((N + 63) / 64);
        // ---- UP branch (lives in bufA) ----
        const float* aggUp = nullptr;
        if (upE > 0) {
            hipMemsetAsync(bufA, 0, (size_t)N * 64 * sizeof(float), stream);
            scatter_add_k<<<(upE * 16 + 255) / 256, 256, 0, stream>>>(x, upSrc, upDst, bufA, upE);
            aggUp = bufA;
        }
        gemm_bn_k<<<gblk, 256, 0, stream>>>(0, aggUp, x,
            nullptr, nullptr, nullptr, nullptr, nullptr, nullptr,
            epsP, d, up_W1 + (size_t)d * 4096, up_b1 + d * 64, bufA, S(d, 0), N);
        gemm_bn_k<<<gblk, 256, 0, stream>>>(1, bufA, nullptr,
            S(d, 0), up_g1 + d * 64, up_be1 + d * 64, nullptr, nullptr, nullptr,
            nullptr, 0, up_W2 + (size_t)d * 4096, up_b2 + d * 64, bufA, S(d, 1), N);
        // ---- BD branch (lives in bufB = out region, dead until final apply) ----
        const float* aggBd = nullptr;
        if (bdE > 0) {
            hipMemsetAsync(bufB, 0, (size_t)N * 64 * sizeof(float), stream);
            scatter_add_k<<<(bdE * 16 + 255) / 256, 256, 0, stream>>>(bdX, bdSrc, bdDst, bufB, bdE);
            aggBd = bufB;
        }
        gemm_bn_k<<<gblk, 256, 0, stream>>>(0, aggBd, x,
            nullptr, nullptr, nullptr, nullptr, nullptr, nullptr,
            epsP, d, bd_W1 + (size_t)d * 4096, bd_b1 + d * 64, bufB, S(d, 2), N);
        gemm_bn_k<<<gblk, 256, 0, stream>>>(1, bufB, nullptr,
            S(d, 2), bd_g1 + d * 64, bd_be1 + d * 64, nullptr, nullptr, nullptr,
            nullptr, 0, bd_W2 + (size_t)d * 4096, bd_b2 + d * 64, bufB, S(d, 3), N);
        // ---- CMB: concat(bn-relu(bufA), bn-relu(bufB)) @ cmb_W -> bufA ----
        gemm_bn_k<<<gblk, 256, 0, stream>>>(2, bufA, bufB,
            S(d, 1), up_g2 + d * 64, up_be2 + d * 64,
            S(d, 3), bd_g2 + d * 64, bd_be2 + d * 64,
            nullptr, 0, cmb_W + (size_t)d * 8192, cmb_b + d * 64, bufA, S(d, 4), N);
        // ---- final BN+ReLU -> output region ----
        bn_relu_apply_k<<<(N * 16 + 255) / 256, 256, 0, stream>>>(
            bufA, S(d, 4), cmb_g + d * 64, cmb_be + d * 64, bufB, N);
    };

    // level 0: upper adjacency only
    runLevel(0, x0, n0, up_index0, up_index0 + EU0, EU0,
             nullptr, nullptr, nullptr, 0, outP);
    // level 1: upper adjacency + node boundaries (boundary attr = x0)
    runLevel(1, x1, n1, up_index1, up_index1 + EU1, EU1,
             x0, bnd_src1, bnd_dst1, EB1, outP + (size_t)n0 * 64);
    // level 2: edge boundaries only (boundary attr = x1)
    runLevel(2, x2, n2, nullptr, nullptr, 0,
             x1, bnd_src2, bnd_dst2, EB2, outP + (size_t)(n0 + n1) * 64);
}

// Round 2
// 2511.417 us; speedup vs baseline: 2.0311x; 2.0311x over previous
//
#include <hip/hip_runtime.h>
#include <cstdint>
#include <cstddef>

// ---------------------------------------------------------------------------
// SparseCINConv: 3 levels of {segment_sum aggregation -> 2x MLP(64->64->64 with
// BatchNorm(batch stats)+ReLU) -> concat -> Linear(128->64)+BN+ReLU}
// All fp32. Aggregation done via on-device CSR build + gather fused into the
// first GEMM of each branch (no float atomics). BN stats fused into GEMM
// epilogues; consumers derive coeffs from global stats.
// ---------------------------------------------------------------------------

// ---------------- CSR build ----------------

__global__ __launch_bounds__(256) void hist_k(const int* __restrict__ dst,
                                              int* __restrict__ cnt, int E) {
    int e = blockIdx.x * 256 + threadIdx.x;
    if (e < E) atomicAdd(&cnt[dst[e]], 1);
}

// in-place exclusive scan, 1024 elems/block, phase A: local scan + block sums
__global__ __launch_bounds__(256) void scanA_k(int* __restrict__ a,
                                               int* __restrict__ bsum, int n) {
    __shared__ int ts[256];
    int tid = threadIdx.x;
    int base = blockIdx.x * 1024 + tid * 4;
    int v[4]; int s = 0;
    #pragma unroll
    for (int i = 0; i < 4; ++i) { v[i] = (base + i < n) ? a[base + i] : 0; s += v[i]; }
    ts[tid] = s;
    __syncthreads();
    for (int off = 1; off < 256; off <<= 1) {
        int t = (tid >= off) ? ts[tid - off] : 0;
        __syncthreads();
        ts[tid] += t;
        __syncthreads();
    }
    int excl = ts[tid] - s;   // exclusive prefix of this thread within block
    int run = excl;
    #pragma unroll
    for (int i = 0; i < 4; ++i) {
        if (base + i < n) { int o = v[i]; a[base + i] = run; run += o; }
    }
    if (tid == 255) bsum[blockIdx.x] = ts[255];
}

__global__ __launch_bounds__(512) void scanB_k(int* __restrict__ bsum, int nb) {
    __shared__ int ls[512];
    int tid = threadIdx.x;
    int v = (tid < nb) ? bsum[tid] : 0;
    ls[tid] = v;
    __syncthreads();
    for (int off = 1; off < 512; off <<= 1) {
        int t = (tid >= off) ? ls[tid - off] : 0;
        __syncthreads();
        ls[tid] += t;
        __syncthreads();
    }
    if (tid < nb) bsum[tid] = ls[tid] - v;  // exclusive
}

__global__ __launch_bounds__(256) void scanC_k(int* __restrict__ a,
                                               const int* __restrict__ bsum, int n) {
    int base = blockIdx.x * 1024 + threadIdx.x * 4;
    int add = bsum[blockIdx.x];
    #pragma unroll
    for (int i = 0; i < 4; ++i)
        if (base + i < n) a[base + i] += add;
}

// scatter edge src ids into CSR slots; cur holds exclusive starts, ends as ends
__global__ __launch_bounds__(256) void fill_k(const int* __restrict__ src,
                                              const int* __restrict__ dst,
                                              int* __restrict__ cur,
                                              int* __restrict__ esrc, int E) {
    int e = blockIdx.x * 256 + threadIdx.x;
    if (e < E) {
        int d = dst[e];
        int pos = atomicAdd(&cur[d], 1);
        esrc[pos] = src[e];
    }
}

// ---------------- fused GEMM + BN-stats ----------------
// mode 0: in = csr_gather(xs) + (1+eps[epsIdx]) * in1              (K=64)
// mode 1: in = relu(bn(in0)) via st0/g0/be0                         (K=64)
// mode 2: in = concat(relu(bn(in0)), relu(bn(in1)))                 (K=128)
// out = in @ W + bias ; ostats[0:64]+=colsum(out), [64:128]+=colsumsq(out)
__global__ __launch_bounds__(256) void gemm_bn_k(
    int mode,
    const int* __restrict__ cur, const int* __restrict__ esrc,
    const float* __restrict__ xs,
    const float* in0, const float* in1,
    const float* __restrict__ st0, const float* __restrict__ g0, const float* __restrict__ be0,
    const float* __restrict__ st1, const float* __restrict__ g1, const float* __restrict__ be1,
    const float* __restrict__ epsP, int epsIdx,
    const float* __restrict__ W, const float* __restrict__ bias,
    float* out, float* __restrict__ ostats, int N)
{
    __shared__ float sIn[64][68];   // padded
    __shared__ float sW[64][64];
    __shared__ float sCoef[4][64];
    __shared__ float sBias[64];
    __shared__ float sRed[16][64];

    const int tid = threadIdx.x;
    const int tx = tid & 15, ty = tid >> 4;
    const int row0 = blockIdx.x * 64;
    const float Nf = (float)N;

    if (tid < 64) {
        sBias[tid] = bias[tid];
        if (mode >= 1) {
            float s = st0[tid], sq = st0[64 + tid];
            float m = s / Nf;
            float v = sq / Nf - m * m;
            float a = g0[tid] * rsqrtf(v + 1e-5f);
            sCoef[0][tid] = a;
            sCoef[1][tid] = be0[tid] - a * m;
        }
    } else if (tid < 128 && mode == 2) {
        int k = tid - 64;
        float s = st1[k], sq = st1[64 + k];
        float m = s / Nf;
        float v = sq / Nf - m * m;
        float a = g1[k] * rsqrtf(v + 1e-5f);
        sCoef[2][k] = a;
        sCoef[3][k] = be1[k] - a * m;
    }
    float sx = 0.f;
    if (mode == 0) sx = 1.0f + epsP[epsIdx];
    __syncthreads();

    float acc[4][4] = {};
    const int nch = (mode == 2) ? 2 : 1;
    for (int ch = 0; ch < nch; ++ch) {
        if (mode == 0) {
            // gather staging: 16 groups of 16 lanes; group g covers rows 4g..4g+3
            int grp = tid >> 4, lane = tid & 15;
            #pragma unroll
            for (int rr = 0; rr < 4; ++rr) {
                int r = grp * 4 + rr;
                int gr = row0 + r;
                float4 a4 = make_float4(0.f, 0.f, 0.f, 0.f);
                if (gr < N) {
                    if (cur) {
                        int s0 = (gr == 0) ? 0 : cur[gr - 1];
                        int s1 = cur[gr];
                        for (int e = s0; e < s1; ++e) {
                            int si = esrc[e];
                            float4 v = *(const float4*)(xs + (size_t)si * 64 + lane * 4);
                            a4.x += v.x; a4.y += v.y; a4.z += v.z; a4.w += v.w;
                        }
                    }
                    float4 xv = *(const float4*)(in1 + (size_t)gr * 64 + lane * 4);
                    a4.x += sx * xv.x; a4.y += sx * xv.y;
                    a4.z += sx * xv.z; a4.w += sx * xv.w;
                }
                *(float4*)&sIn[r][lane * 4] = a4;
            }
        } else {
            for (int t = tid; t < 1024; t += 256) {
                int r = t >> 4, f4 = t & 15;
                int gr = row0 + r;
                int col = f4 * 4;
                float4 v = make_float4(0.f, 0.f, 0.f, 0.f);
                if (gr < N) {
                    const float* base = (ch == 0) ? in0 : in1;
                    float4 yv = *(const float4*)(base + (size_t)gr * 64 + col);
                    int ci = ch * 2;
                    v.x = fmaxf(sCoef[ci][col+0]*yv.x + sCoef[ci+1][col+0], 0.f);
                    v.y = fmaxf(sCoef[ci][col+1]*yv.y + sCoef[ci+1][col+1], 0.f);
                    v.z = fmaxf(sCoef[ci][col+2]*yv.z + sCoef[ci+1][col+2], 0.f);
                    v.w = fmaxf(sCoef[ci][col+3]*yv.w + sCoef[ci+1][col+3], 0.f);
                }
                *(float4*)&sIn[r][col] = v;
            }
        }
        for (int t = tid; t < 1024; t += 256) {
            int r = t >> 4, f4 = t & 15;
            *(float4*)&sW[r][f4 * 4] =
                *(const float4*)(W + (size_t)(ch * 64 + r) * 64 + f4 * 4);
        }
        __syncthreads();
        #pragma unroll
        for (int kb = 0; kb < 64; kb += 4) {
            float4 xf[4], wf[4];
            #pragma unroll
            for (int i = 0; i < 4; ++i) xf[i] = *(const float4*)&sIn[4*ty + i][kb];
            #pragma unroll
            for (int kk = 0; kk < 4; ++kk) wf[kk] = *(const float4*)&sW[kb + kk][4*tx];
            const float* xff = (const float*)xf;
            const float* wff = (const float*)wf;
            #pragma unroll
            for (int kk = 0; kk < 4; ++kk) {
                #pragma unroll
                for (int i = 0; i < 4; ++i) {
                    float xv = xff[i*4 + kk];
                    #pragma unroll
                    for (int j = 0; j < 4; ++j)
                        acc[i][j] = fmaf(xv, wff[kk*4 + j], acc[i][j]);
                }
            }
        }
        __syncthreads();
    }

    // epilogue: bias add, store, column stats
    float ps[4] = {0,0,0,0}, pq[4] = {0,0,0,0};
    #pragma unroll
    for (int i = 0; i < 4; ++i) {
        int gr = row0 + 4*ty + i;
        if (gr < N) {
            float4 o;
            o.x = acc[i][0] + sBias[4*tx+0];
            o.y = acc[i][1] + sBias[4*tx+1];
            o.z = acc[i][2] + sBias[4*tx+2];
            o.w = acc[i][3] + sBias[4*tx+3];
            *(float4*)(out + (size_t)gr * 64 + 4*tx) = o;
            ps[0]+=o.x; ps[1]+=o.y; ps[2]+=o.z; ps[3]+=o.w;
            pq[0]+=o.x*o.x; pq[1]+=o.y*o.y; pq[2]+=o.z*o.z; pq[3]+=o.w*o.w;
        }
    }
    *(float4*)&sRed[ty][4*tx] = make_float4(ps[0],ps[1],ps[2],ps[3]);
    __syncthreads();
    if (tid < 64) {
        float s = 0.f;
        #pragma unroll
        for (int t = 0; t < 16; ++t) s += sRed[t][tid];
        unsafeAtomicAdd(&ostats[tid], s);
    }
    __syncthreads();
    *(float4*)&sRed[ty][4*tx] = make_float4(pq[0],pq[1],pq[2],pq[3]);
    __syncthreads();
    if (tid < 64) {
        float s = 0.f;
        #pragma unroll
        for (int t = 0; t < 16; ++t) s += sRed[t][tid];
        unsafeAtomicAdd(&ostats[64 + tid], s);
    }
}

__global__ __launch_bounds__(256) void bn_relu_apply_k(
    const float* __restrict__ y, const float* __restrict__ st,
    const float* __restrict__ g, const float* __restrict__ be,
    float* __restrict__ out, int N)
{
    __shared__ float sa[64], sc[64];
    int tid = threadIdx.x;
    if (tid < 64) {
        float s = st[tid], sq = st[64 + tid];
        float m = s / (float)N;
        float v = sq / (float)N - m * m;
        float a = g[tid] * rsqrtf(v + 1e-5f);
        sa[tid] = a;
        sc[tid] = be[tid] - a * m;
    }
    __syncthreads();
    int idx = blockIdx.x * 256 + tid;
    if (idx < N * 16) {
        int r = idx >> 4, f4 = idx & 15, col = f4 * 4;
        float4 v = *(const float4*)(y + (size_t)r * 64 + col);
        float4 o;
        o.x = fmaxf(sa[col+0]*v.x + sc[col+0], 0.f);
        o.y = fmaxf(sa[col+1]*v.y + sc[col+1], 0.f);
        o.z = fmaxf(sa[col+2]*v.z + sc[col+2], 0.f);
        o.w = fmaxf(sa[col+3]*v.w + sc[col+3], 0.f);
        *(float4*)(out + (size_t)r * 64 + col) = o;
    }
}

extern "C" void kernel_launch(void* const* d_in, const int* in_sizes, int n_in,
                              void* d_out, int out_size, void* d_ws, size_t ws_size,
                              hipStream_t stream) {
    (void)n_in; (void)out_size; (void)ws_size;
    const float* x0 = (const float*)d_in[0];
    const float* x1 = (const float*)d_in[1];
    const float* x2 = (const float*)d_in[2];
    const int* up_index0 = (const int*)d_in[3];
    const int* up_index1 = (const int*)d_in[4];
    const int* bnd_src1  = (const int*)d_in[5];
    const int* bnd_dst1  = (const int*)d_in[6];
    const int* bnd_src2  = (const int*)d_in[7];
    const int* bnd_dst2  = (const int*)d_in[8];
    const float* up_W1 = (const float*)d_in[9];
    const float* up_b1 = (const float*)d_in[10];
    const float* up_g1 = (const float*)d_in[11];
    const float* up_be1= (const float*)d_in[12];
    const float* up_W2 = (const float*)d_in[13];
    const float* up_b2 = (const float*)d_in[14];
    const float* up_g2 = (const float*)d_in[15];
    const float* up_be2= (const float*)d_in[16];
    const float* bd_W1 = (const float*)d_in[17];
    const float* bd_b1 = (const float*)d_in[18];
    const float* bd_g1 = (const float*)d_in[19];
    const float* bd_be1= (const float*)d_in[20];
    const float* bd_W2 = (const float*)d_in[21];
    const float* bd_b2 = (const float*)d_in[22];
    const float* bd_g2 = (const float*)d_in[23];
    const float* bd_be2= (const float*)d_in[24];
    const float* cmb_W = (const float*)d_in[25];
    const float* cmb_b = (const float*)d_in[26];
    const float* cmb_g = (const float*)d_in[27];
    const float* cmb_be= (const float*)d_in[28];
    const float* epsP  = (const float*)d_in[29];

    const int EU0 = in_sizes[3] / 2, EU1 = in_sizes[4] / 2;
    const int EB1 = in_sizes[5],     EB2 = in_sizes[7];
    const int n0 = in_sizes[0] / 64, n1 = in_sizes[1] / 64, n2 = in_sizes[2] / 64;

    float* outP  = (float*)d_out;
    float* bufA  = (float*)d_ws;                     // n1*64 floats
    float* stats = bufA + (size_t)n1 * 64;           // 15*128 floats
    int*   bsum  = (int*)(stats + 15 * 128);         // 1024 ints scan scratch

    // CSR storage lives in the out2 region (dead until level-2 final apply).
    // 4.9M ints needed, 6.4M floats available.
    int* csr      = (int*)(outP + (size_t)(n0 + n1) * 64);
    int* curEU0   = csr;
    int* curEU1   = curEU0 + n0;
    int* curEB1   = curEU1 + n1;
    int* curEB2   = curEB1 + n1;
    int* esrcEU0  = curEB2 + n2;
    int* esrcEU1  = esrcEU0 + EU0;
    int* esrcEB1  = esrcEU1 + EU1;
    int* esrcEB2  = esrcEB1 + EB1;

    hipMemsetAsync(stats, 0, 15 * 128 * sizeof(float), stream);

    auto buildCSR = [&](const int* src, const int* dst, int E, int* cur, int* esrc, int N) {
        hipMemsetAsync(cur, 0, (size_t)N * sizeof(int), stream);
        hist_k<<<(E + 255) / 256, 256, 0, stream>>>(dst, cur, E);
        int nb = (N + 1023) / 1024;
        scanA_k<<<nb, 256, 0, stream>>>(cur, bsum, N);
        scanB_k<<<1, 512, 0, stream>>>(bsum, nb);
        scanC_k<<<nb, 256, 0, stream>>>(cur, bsum, N);
        fill_k<<<(E + 255) / 256, 256, 0, stream>>>(src, dst, cur, esrc, E);
    };

    buildCSR(up_index0, up_index0 + EU0, EU0, curEU0, esrcEU0, n0);
    buildCSR(up_index1, up_index1 + EU1, EU1, curEU1, esrcEU1, n1);
    buildCSR(bnd_src1,  bnd_dst1,        EB1, curEB1, esrcEB1, n1);
    buildCSR(bnd_src2,  bnd_dst2,        EB2, curEB2, esrcEB2, n2);

    auto S = [&](int d, int i) { return stats + (size_t)(d * 5 + i) * 128; };

    // hUp / hBd: per-branch intermediate buffers. cmb writes in-place over hUp;
    // apply writes the level's out region.
    auto runLevel = [&](int d, const float* x, int N,
                        const int* curUp, const int* esUp,
                        const int* curBd, const int* esBd, const float* bdX,
                        float* hUp, float* hBd, float* outR) {
        dim3 gblk((N + 63) / 64);
        gemm_bn_k<<<gblk, 256, 0, stream>>>(0, curUp, esUp, x, nullptr, x,
            nullptr, nullptr, nullptr, nullptr, nullptr, nullptr,
            epsP, d, up_W1 + (size_t)d * 4096, up_b1 + d * 64, hUp, S(d, 0), N);
        gemm_bn_k<<<gblk, 256, 0, stream>>>(1, nullptr, nullptr, nullptr, hUp, nullptr,
            S(d, 0), up_g1 + d * 64, up_be1 + d * 64, nullptr, nullptr, nullptr,
            nullptr, 0, up_W2 + (size_t)d * 4096, up_b2 + d * 64, hUp, S(d, 1), N);
        gemm_bn_k<<<gblk, 256, 0, stream>>>(0, curBd, esBd, bdX, nullptr, x,
            nullptr, nullptr, nullptr, nullptr, nullptr, nullptr,
            epsP, d, bd_W1 + (size_t)d * 4096, bd_b1 + d * 64, hBd, S(d, 2), N);
        gemm_bn_k<<<gblk, 256, 0, stream>>>(1, nullptr, nullptr, nullptr, hBd, nullptr,
            S(d, 2), bd_g1 + d * 64, bd_be1 + d * 64, nullptr, nullptr, nullptr,
            nullptr, 0, bd_W2 + (size_t)d * 4096, bd_b2 + d * 64, hBd, S(d, 3), N);
        gemm_bn_k<<<gblk, 256, 0, stream>>>(2, nullptr, nullptr, nullptr, hUp, hBd,
            S(d, 1), up_g2 + d * 64, up_be2 + d * 64,
            S(d, 3), bd_g2 + d * 64, bd_be2 + d * 64,
            nullptr, 0, cmb_W + (size_t)d * 8192, cmb_b + d * 64, hUp, S(d, 4), N);
        bn_relu_apply_k<<<(N * 16 + 255) / 256, 256, 0, stream>>>(
            hUp, S(d, 4), cmb_g + d * 64, cmb_be + d * 64, outR, N);
    };

    // level 0: up adjacency only; both intermediates in bufA slices
    runLevel(0, x0, n0, curEU0, esrcEU0, nullptr, nullptr, nullptr,
             bufA, bufA + (size_t)n0 * 64, outP);
    // level 1: up adjacency + node boundaries; hBd in out1 region
    runLevel(1, x1, n1, curEU1, esrcEU1, curEB1, esrcEB1, x0,
             bufA, outP + (size_t)n0 * 64, outP + (size_t)n0 * 64);
    // level 2: edge boundaries only; both intermediates in bufA slices
    // (out2 still holds the EB2 CSR until the bd gemm consumes it)
    runLevel(2, x2, n2, nullptr, nullptr, curEB2, esrcEB2, x1,
             bufA, bufA + (size_t)n2 * 64, outP + (size_t)(n0 + n1) * 64);
}

// Round 3
// 2166.336 us; speedup vs baseline: 2.3546x; 1.1593x over previous
//
#include <hip/hip_runtime.h>
#include <cstdint>
#include <cstddef>

// ---------------------------------------------------------------------------
// SparseCINConv, MFMA edition: CSR-gather fused into first GEMM, all GEMMs on
// mfma_f32_16x16x32_bf16 (fp32 accumulate), intermediates stored bf16,
// BN batch-stats accumulated fp32 in GEMM epilogues.
// ---------------------------------------------------------------------------

using bfrag = __attribute__((ext_vector_type(8))) short;   // 8 bf16 (4 VGPRs)
using f32x4 = __attribute__((ext_vector_type(4))) float;   // 4 fp32 acc

__device__ __forceinline__ unsigned short f2bf(float f) {
    unsigned int u = __float_as_uint(f);
    u += 0x7FFFu + ((u >> 16) & 1u);          // RNE
    return (unsigned short)(u >> 16);
}
__device__ __forceinline__ float bf2f(unsigned int h) {
    return __uint_as_float(h << 16);
}

// ---------------- CSR build ----------------

__global__ __launch_bounds__(256) void hist_k(const int* __restrict__ dst,
                                              int* __restrict__ cnt, int E) {
    int e = blockIdx.x * 256 + threadIdx.x;
    if (e < E) atomicAdd(&cnt[dst[e]], 1);
}

__global__ __launch_bounds__(256) void scanA_k(int* __restrict__ a,
                                               int* __restrict__ bsum, int n) {
    __shared__ int ts[256];
    int tid = threadIdx.x;
    int base = blockIdx.x * 1024 + tid * 4;
    int v[4]; int s = 0;
    #pragma unroll
    for (int i = 0; i < 4; ++i) { v[i] = (base + i < n) ? a[base + i] : 0; s += v[i]; }
    ts[tid] = s;
    __syncthreads();
    for (int off = 1; off < 256; off <<= 1) {
        int t = (tid >= off) ? ts[tid - off] : 0;
        __syncthreads();
        ts[tid] += t;
        __syncthreads();
    }
    int run = ts[tid] - s;
    #pragma unroll
    for (int i = 0; i < 4; ++i) {
        if (base + i < n) { int o = v[i]; a[base + i] = run; run += o; }
    }
    if (tid == 255) bsum[blockIdx.x] = ts[255];
}

__global__ __launch_bounds__(512) void scanB_k(int* __restrict__ bsum, int nb) {
    __shared__ int ls[512];
    int tid = threadIdx.x;
    int v = (tid < nb) ? bsum[tid] : 0;
    ls[tid] = v;
    __syncthreads();
    for (int off = 1; off < 512; off <<= 1) {
        int t = (tid >= off) ? ls[tid - off] : 0;
        __syncthreads();
        ls[tid] += t;
        __syncthreads();
    }
    if (tid < nb) bsum[tid] = ls[tid] - v;
}

__global__ __launch_bounds__(256) void scanC_k(int* __restrict__ a,
                                               const int* __restrict__ bsum, int n) {
    int base = blockIdx.x * 1024 + threadIdx.x * 4;
    int add = bsum[blockIdx.x];
    #pragma unroll
    for (int i = 0; i < 4; ++i)
        if (base + i < n) a[base + i] += add;
}

__global__ __launch_bounds__(256) void fill_k(const int* __restrict__ src,
                                              const int* __restrict__ dst,
                                              int* __restrict__ cur,
                                              int* __restrict__ esrc, int E) {
    int e = blockIdx.x * 256 + threadIdx.x;
    if (e < E) {
        int d = dst[e];
        int pos = atomicAdd(&cur[d], 1);
        esrc[pos] = src[e];
    }
}

// ---------------- weight prep: fp32 [K][64] -> bf16 transposed [64][K] -------

__global__ __launch_bounds__(256) void wprep_k(
    const float* __restrict__ upW1, const float* __restrict__ upW2,
    const float* __restrict__ bdW1, const float* __restrict__ bdW2,
    const float* __restrict__ cmbW, unsigned short* __restrict__ wT)
{
    int id = blockIdx.x;        // 0..14 = d*5 + j
    int d = id / 5, j = id % 5;
    const float* src; int K = 64;
    if (j == 0)      src = upW1 + (size_t)d * 4096;
    else if (j == 1) src = upW2 + (size_t)d * 4096;
    else if (j == 2) src = bdW1 + (size_t)d * 4096;
    else if (j == 3) src = bdW2 + (size_t)d * 4096;
    else           { src = cmbW + (size_t)d * 8192; K = 128; }
    unsigned short* dst = wT + (size_t)d * 24576 + (j < 4 ? j * 4096 : 16384);
    for (int e = threadIdx.x; e < K * 64; e += 256) {
        int k = e >> 6, n = e & 63;
        dst[n * K + k] = f2bf(src[e]);
    }
}

// ---------------- fused MFMA GEMM + BN-stats ----------------
// mode 0: A = csr_gather(xs) + (1+eps)*xself   (fp32 in, K=64)
// mode 1: A = relu(bn(in0))                     (bf16 in, K=64)
// mode 2: A = concat(relu(bn(in0)),relu(bn(in1))) (bf16 in, K=128)
// out(bf16) = A @ W + bias ; ostats += {colsum, colsumsq} (fp32)
__global__ __launch_bounds__(256) void gemm_bn_k(
    int mode,
    const int* __restrict__ cur, const int* __restrict__ esrc,
    const float* __restrict__ xs, const float* __restrict__ xself,
    const unsigned short* __restrict__ in0, const unsigned short* __restrict__ in1,
    const float* __restrict__ st0, const float* __restrict__ g0, const float* __restrict__ be0,
    const float* __restrict__ st1, const float* __restrict__ g1, const float* __restrict__ be1,
    const float* __restrict__ epsP, int epsIdx,
    const unsigned short* __restrict__ wT, const float* __restrict__ bias,
    unsigned short* __restrict__ out, float* __restrict__ ostats, int N)
{
    __shared__ unsigned short sIn[64][72];  // +8 pad: fragment reads 2-way (free)
    __shared__ unsigned short sW[64][72];   // W transposed [n][k]
    __shared__ float sCoef[4][64];
    __shared__ float sBias[64];
    __shared__ float sRedS[4][64];
    __shared__ float sRedQ[4][64];

    const int tid = threadIdx.x;
    const int row0 = blockIdx.x * 64;
    const float Nf = (float)N;

    if (tid < 64) {
        sBias[tid] = bias[tid];
        if (mode >= 1) {
            float s = st0[tid], sq = st0[64 + tid];
            float m = s / Nf, v = sq / Nf - m * m;
            float a = g0[tid] * rsqrtf(v + 1e-5f);
            sCoef[0][tid] = a; sCoef[1][tid] = be0[tid] - a * m;
        }
    } else if (tid < 128 && mode == 2) {
        int k = tid - 64;
        float s = st1[k], sq = st1[64 + k];
        float m = s / Nf, v = sq / Nf - m * m;
        float a = g1[k] * rsqrtf(v + 1e-5f);
        sCoef[2][k] = a; sCoef[3][k] = be1[k] - a * m;
    }
    const float sx = (mode == 0) ? (1.0f + epsP[epsIdx]) : 0.f;
    __syncthreads();

    f32x4 acc[4] = {};
    const int K = (mode == 2) ? 128 : 64;
    const int nch = (mode == 2) ? 2 : 1;
    const int wv = tid >> 6, l = tid & 63, l15 = l & 15, quad = l >> 4;

    for (int ch = 0; ch < nch; ++ch) {
        if (ch) __syncthreads();   // LDS reuse between chunks
        if (mode == 0) {
            int grp = tid >> 4, lane = tid & 15;
            for (int rr = 0; rr < 4; ++rr) {
                int r = grp * 4 + rr;
                int gr = row0 + r;
                float ax = 0.f, ay = 0.f, az = 0.f, aw = 0.f;
                if (gr < N) {
                    if (cur) {
                        int s0 = (gr == 0) ? 0 : cur[gr - 1];
                        int s1 = cur[gr];
                        int e = s0;
                        for (; e + 1 < s1; e += 2) {   // 2-wide: overlap load latency
                            int si0 = esrc[e], si1 = esrc[e + 1];
                            float4 v0 = *(const float4*)(xs + (size_t)si0 * 64 + lane * 4);
                            float4 v1 = *(const float4*)(xs + (size_t)si1 * 64 + lane * 4);
                            ax += v0.x + v1.x; ay += v0.y + v1.y;
                            az += v0.z + v1.z; aw += v0.w + v1.w;
                        }
                        if (e < s1) {
                            int si = esrc[e];
                            float4 v0 = *(const float4*)(xs + (size_t)si * 64 + lane * 4);
                            ax += v0.x; ay += v0.y; az += v0.z; aw += v0.w;
                        }
                    }
                    float4 xv = *(const float4*)(xself + (size_t)gr * 64 + lane * 4);
                    ax = fmaf(sx, xv.x, ax); ay = fmaf(sx, xv.y, ay);
                    az = fmaf(sx, xv.z, az); aw = fmaf(sx, xv.w, aw);
                }
                ushort4 pk;
                pk.x = f2bf(ax); pk.y = f2bf(ay); pk.z = f2bf(az); pk.w = f2bf(aw);
                *(ushort4*)&sIn[r][lane * 4] = pk;
            }
        } else {
            const unsigned short* base = ch ? in1 : in0;
            const int ci = ch * 2;
            #pragma unroll
            for (int it = 0; it < 2; ++it) {
                int id = tid + it * 256;
                int r = id >> 3, c8 = id & 7;
                int gr = row0 + r;
                uint4 pk = {0u, 0u, 0u, 0u};
                if (gr < N) {
                    uint4 raw = *(const uint4*)(base + (size_t)gr * 64 + c8 * 8);
                    unsigned int rw[4] = {raw.x, raw.y, raw.z, raw.w};
                    unsigned int ow[4];
                    #pragma unroll
                    for (int q2 = 0; q2 < 4; ++q2) {
                        int col = c8 * 8 + q2 * 2;
                        float v0 = fmaxf(fmaf(sCoef[ci][col], bf2f(rw[q2] & 0xFFFFu),
                                              sCoef[ci + 1][col]), 0.f);
                        float v1 = fmaxf(fmaf(sCoef[ci][col + 1], bf2f(rw[q2] >> 16),
                                              sCoef[ci + 1][col + 1]), 0.f);
                        ow[q2] = (unsigned int)f2bf(v0) | ((unsigned int)f2bf(v1) << 16);
                    }
                    pk.x = ow[0]; pk.y = ow[1]; pk.z = ow[2]; pk.w = ow[3];
                }
                *(uint4*)&sIn[r][c8 * 8] = pk;
            }
        }
        #pragma unroll
        for (int it = 0; it < 2; ++it) {
            int id = tid + it * 256;
            int nr = id >> 3, c8 = id & 7;
            uint4 w = *(const uint4*)(wT + (size_t)nr * K + ch * 64 + c8 * 8);
            *(uint4*)&sW[nr][c8 * 8] = w;
        }
        __syncthreads();
        // A frag: A[m=lane&15][k=quad*8+j]; B frag: B[k=quad*8+j][n=lane&15]
        bfrag a0 = *(const bfrag*)&sIn[16 * wv + l15][quad * 8];
        bfrag a1 = *(const bfrag*)&sIn[16 * wv + l15][32 + quad * 8];
        #pragma unroll
        for (int c = 0; c < 4; ++c) {
            bfrag b0 = *(const bfrag*)&sW[16 * c + l15][quad * 8];
            bfrag b1 = *(const bfrag*)&sW[16 * c + l15][32 + quad * 8];
            acc[c] = __builtin_amdgcn_mfma_f32_16x16x32_bf16(a0, b0, acc[c], 0, 0, 0);
            acc[c] = __builtin_amdgcn_mfma_f32_16x16x32_bf16(a1, b1, acc[c], 0, 0, 0);
        }
    }

    // epilogue: bias, bf16 store, fp32 column stats
    // C/D layout: col = lane&15 (+16c), row = quad*4 + reg (+16*wv)
    float psv[4], pqv[4];
    #pragma unroll
    for (int c = 0; c < 4; ++c) {
        int col = 16 * c + l15;
        float b = sBias[col];
        float ps = 0.f, pq = 0.f;
        #pragma unroll
        for (int r = 0; r < 4; ++r) {
            int grow = row0 + 16 * wv + quad * 4 + r;
            if (grow < N) {
                float v = acc[c][r] + b;
                out[(size_t)grow * 64 + col] = f2bf(v);
                ps += v; pq += v * v;
            }
        }
        psv[c] = ps; pqv[c] = pq;
    }
    #pragma unroll
    for (int c = 0; c < 4; ++c) {
        float ps = psv[c], pq = pqv[c];
        ps += __shfl_xor(ps, 16, 64); pq += __shfl_xor(pq, 16, 64);
        ps += __shfl_xor(ps, 32, 64); pq += __shfl_xor(pq, 32, 64);
        if (l < 16) { sRedS[wv][16 * c + l] = ps; sRedQ[wv][16 * c + l] = pq; }
    }
    __syncthreads();
    if (tid < 64) {
        float s = sRedS[0][tid] + sRedS[1][tid] + sRedS[2][tid] + sRedS[3][tid];
        float q = sRedQ[0][tid] + sRedQ[1][tid] + sRedQ[2][tid] + sRedQ[3][tid];
        unsafeAtomicAdd(&ostats[tid], s);
        unsafeAtomicAdd(&ostats[64 + tid], q);
    }
}

__global__ __launch_bounds__(256) void bn_relu_apply_k(
    const unsigned short* __restrict__ y, const float* __restrict__ st,
    const float* __restrict__ g, const float* __restrict__ be,
    float* __restrict__ out, int N)
{
    __shared__ float sa[64], sc[64];
    int tid = threadIdx.x;
    if (tid < 64) {
        float s = st[tid], sq = st[64 + tid];
        float m = s / (float)N, v = sq / (float)N - m * m;
        float a = g[tid] * rsqrtf(v + 1e-5f);
        sa[tid] = a; sc[tid] = be[tid] - a * m;
    }
    __syncthreads();
    int idx = blockIdx.x * 256 + tid;
    if (idx < N * 8) {
        int r = idx >> 3, c8 = idx & 7;
        uint4 raw = *(const uint4*)(y + (size_t)r * 64 + c8 * 8);
        unsigned int rw[4] = {raw.x, raw.y, raw.z, raw.w};
        float o[8];
        #pragma unroll
        for (int q = 0; q < 4; ++q) {
            int col = c8 * 8 + q * 2;
            o[q * 2 + 0] = fmaxf(fmaf(sa[col + 0], bf2f(rw[q] & 0xFFFFu), sc[col + 0]), 0.f);
            o[q * 2 + 1] = fmaxf(fmaf(sa[col + 1], bf2f(rw[q] >> 16), sc[col + 1]), 0.f);
        }
        float4 o0 = {o[0], o[1], o[2], o[3]}, o1 = {o[4], o[5], o[6], o[7]};
        *(float4*)(out + (size_t)r * 64 + c8 * 8) = o0;
        *(float4*)(out + (size_t)r * 64 + c8 * 8 + 4) = o1;
    }
}

extern "C" void kernel_launch(void* const* d_in, const int* in_sizes, int n_in,
                              void* d_out, int out_size, void* d_ws, size_t ws_size,
                              hipStream_t stream) {
    (void)n_in; (void)out_size; (void)ws_size;
    const float* x0 = (const float*)d_in[0];
    const float* x1 = (const float*)d_in[1];
    const float* x2 = (const float*)d_in[2];
    const int* up_index0 = (const int*)d_in[3];
    const int* up_index1 = (const int*)d_in[4];
    const int* bnd_src1  = (const int*)d_in[5];
    const int* bnd_dst1  = (const int*)d_in[6];
    const int* bnd_src2  = (const int*)d_in[7];
    const int* bnd_dst2  = (const int*)d_in[8];
    const float* up_W1 = (const float*)d_in[9];
    const float* up_b1 = (const float*)d_in[10];
    const float* up_g1 = (const float*)d_in[11];
    const float* up_be1= (const float*)d_in[12];
    const float* up_W2 = (const float*)d_in[13];
    const float* up_b2 = (const float*)d_in[14];
    const float* up_g2 = (const float*)d_in[15];
    const float* up_be2= (const float*)d_in[16];
    const float* bd_W1 = (const float*)d_in[17];
    const float* bd_b1 = (const float*)d_in[18];
    const float* bd_g1 = (const float*)d_in[19];
    const float* bd_be1= (const float*)d_in[20];
    const float* bd_W2 = (const float*)d_in[21];
    const float* bd_b2 = (const float*)d_in[22];
    const float* bd_g2 = (const float*)d_in[23];
    const float* bd_be2= (const float*)d_in[24];
    const float* cmb_W = (const float*)d_in[25];
    const float* cmb_b = (const float*)d_in[26];
    const float* cmb_g = (const float*)d_in[27];
    const float* cmb_be= (const float*)d_in[28];
    const float* epsP  = (const float*)d_in[29];

    const int EU0 = in_sizes[3] / 2, EU1 = in_sizes[4] / 2;
    const int EB1 = in_sizes[5],     EB2 = in_sizes[7];
    const int n0 = in_sizes[0] / 64, n1 = in_sizes[1] / 64, n2 = in_sizes[2] / 64;
    const int nMax02 = (n0 > n2) ? n0 : n2;

    float* outP = (float*)d_out;

    // ---- ws layout (all 16B-aligned) ----
    unsigned short* bufU = (unsigned short*)d_ws;              // n1*64 bf16
    unsigned short* bufB = bufU + (size_t)n1 * 64;             // max(n0,n2)*64 bf16
    float* stats = (float*)(bufB + (size_t)nMax02 * 64);       // 15*128 fp32
    int*   bsum  = (int*)(stats + 15 * 128);                   // 1024 ints
    unsigned short* wT = (unsigned short*)(bsum + 1024);       // 73728 bf16

    // CSR storage in out2 region (dead until level-2 final apply)
    int* csr      = (int*)(outP + (size_t)(n0 + n1) * 64);
    int* curEU0   = csr;
    int* curEU1   = curEU0 + n0;
    int* curEB1   = curEU1 + n1;
    int* curEB2   = curEB1 + n1;
    int* esrcEU0  = curEB2 + n2;
    int* esrcEU1  = esrcEU0 + EU0;
    int* esrcEB1  = esrcEU1 + EU1;
    int* esrcEB2  = esrcEB1 + EB1;

    // level-1 bd intermediate lives in out1 region (dead until level-1 apply)
    unsigned short* hBd1 = (unsigned short*)(outP + (size_t)n0 * 64);

    hipMemsetAsync(stats, 0, 15 * 128 * sizeof(float), stream);
    wprep_k<<<15, 256, 0, stream>>>(up_W1, up_W2, bd_W1, bd_W2, cmb_W, wT);

    auto buildCSR = [&](const int* src, const int* dst, int E, int* cur, int* esrc, int N) {
        hipMemsetAsync(cur, 0, (size_t)N * sizeof(int), stream);
        hist_k<<<(E + 255) / 256, 256, 0, stream>>>(dst, cur, E);
        int nb = (N + 1023) / 1024;
        scanA_k<<<nb, 256, 0, stream>>>(cur, bsum, N);
        scanB_k<<<1, 512, 0, stream>>>(bsum, nb);
        scanC_k<<<nb, 256, 0, stream>>>(cur, bsum, N);
        fill_k<<<(E + 255) / 256, 256, 0, stream>>>(src, dst, cur, esrc, E);
    };

    buildCSR(up_index0, up_index0 + EU0, EU0, curEU0, esrcEU0, n0);
    buildCSR(up_index1, up_index1 + EU1, EU1, curEU1, esrcEU1, n1);
    buildCSR(bnd_src1,  bnd_dst1,        EB1, curEB1, esrcEB1, n1);
    buildCSR(bnd_src2,  bnd_dst2,        EB2, curEB2, esrcEB2, n2);

    auto S  = [&](int d, int i) { return stats + (size_t)(d * 5 + i) * 128; };
    auto WT = [&](int d, int j) { return wT + (size_t)d * 24576 + (j < 4 ? j * 4096 : 16384); };

    auto runLevel = [&](int d, const float* x, int N,
                        const int* curUp, const int* esUp,
                        const int* curBd, const int* esBd, const float* bdX,
                        unsigned short* hUp, unsigned short* hBd, float* outR) {
        dim3 gblk((N + 63) / 64);
        gemm_bn_k<<<gblk, 256, 0, stream>>>(0, curUp, esUp, x, x, nullptr, nullptr,
            nullptr, nullptr, nullptr, nullptr, nullptr, nullptr,
            epsP, d, WT(d, 0), up_b1 + d * 64, hUp, S(d, 0), N);
        gemm_bn_k<<<gblk, 256, 0, stream>>>(1, nullptr, nullptr, nullptr, nullptr, hUp, nullptr,
            S(d, 0), up_g1 + d * 64, up_be1 + d * 64, nullptr, nullptr, nullptr,
            nullptr, 0, WT(d, 1), up_b2 + d * 64, hUp, S(d, 1), N);
        gemm_bn_k<<<gblk, 256, 0, stream>>>(0, curBd, esBd, bdX, x, nullptr, nullptr,
            nullptr, nullptr, nullptr, nullptr, nullptr, nullptr,
            epsP, d, WT(d, 2), bd_b1 + d * 64, hBd, S(d, 2), N);
        gemm_bn_k<<<gblk, 256, 0, stream>>>(1, nullptr, nullptr, nullptr, nullptr, hBd, nullptr,
            S(d, 2), bd_g1 + d * 64, bd_be1 + d * 64, nullptr, nullptr, nullptr,
            nullptr, 0, WT(d, 3), bd_b2 + d * 64, hBd, S(d, 3), N);
        gemm_bn_k<<<gblk, 256, 0, stream>>>(2, nullptr, nullptr, nullptr, nullptr, hUp, hBd,
            S(d, 1), up_g2 + d * 64, up_be2 + d * 64,
            S(d, 3), bd_g2 + d * 64, bd_be2 + d * 64,
            nullptr, 0, WT(d, 4), cmb_b + d * 64, hUp, S(d, 4), N);
        bn_relu_apply_k<<<(N * 8 + 255) / 256, 256, 0, stream>>>(
            hUp, S(d, 4), cmb_g + d * 64, cmb_be + d * 64, outR, N);
    };

    // level 0: up adjacency only
    runLevel(0, x0, n0, curEU0, esrcEU0, nullptr, nullptr, nullptr,
             bufU, bufB, outP);
    // level 1: up adjacency + node boundaries (boundary attr = x0)
    runLevel(1, x1, n1, curEU1, esrcEU1, curEB1, esrcEB1, x0,
             bufU, hBd1, outP + (size_t)n0 * 64);
    // level 2: edge boundaries only (boundary attr = x1)
    runLevel(2, x2, n2, nullptr, nullptr, curEB2, esrcEB2, x1,
             bufU, bufB, outP + (size_t)(n0 + n1) * 64);
}